// Round 1
// baseline (146.514 us; speedup 1.0000x reference)
//
#include <hip/hip_runtime.h>
#include <hip/hip_fp16.h>
#include <type_traits>

#define LQ 21760
#define MROWS 43520
#define LEN 21760

typedef __attribute__((ext_vector_type(8))) _Float16 half8;
typedef __attribute__((ext_vector_type(4))) float f32x4;

__device__ __forceinline__ uint pkh(float a, float b) {
  auto v = __builtin_amdgcn_cvt_pkrtz(a, b);
  return __builtin_bit_cast(uint, v);
}
__device__ __forceinline__ ushort h16(float x) {
  return __half_as_ushort(__float2half(x));
}
__device__ __forceinline__ float hlo(uint u) {
  return __half2float(__ushort_as_half((ushort)(u & 0xffffu)));
}
__device__ __forceinline__ float hhi(uint u) {
  return __half2float(__ushort_as_half((ushort)(u >> 16)));
}

// ushort index of the 16B slot for (row, k8) with XOR swizzle (<=2-way banks)
__device__ __forceinline__ int swz8(int row, int k8) {
  return row * 32 + ((k8 ^ (row & 3) ^ ((row >> 2) & 3)) << 3);
}

// ---- f16 MFMA GEMM body, double-buffered LDS, 1 barrier per K-step --------
// C[128, BN] = A[128, K=256] @ WT^T + bias. 512 thr = 8 waves (2M x 4N).
template <int BN, bool SPLIT, typename AT, typename OT>
__device__ __forceinline__ void gemm_body(
    const AT* __restrict__ A, int lda, const ushort* __restrict__ WT,
    const float* __restrict__ bias, const float* __restrict__ bias2,
    OT* __restrict__ Cout, int ldc, ushort* __restrict__ C2, int mblk,
    ushort* Asb, ushort* Bsb) {
  constexpr int WN = BN / 4;
  constexpr int NI = WN / 16;
  constexpr int BSTEP = (BN * 4) / 512;
  const int tid = threadIdx.x;
  const int m0 = mblk * 128;
  const int w = tid >> 6, wm = w >> 2, wn = w & 3;
  const int l = tid & 63, lr = l & 15, lk = l >> 4;
  const int arow = tid >> 2, ak8 = tid & 3;

  f32x4 acc[4][NI];
#pragma unroll
  for (int mi = 0; mi < 4; ++mi)
#pragma unroll
    for (int ni = 0; ni < NI; ++ni) acc[mi][ni] = {0.f, 0.f, 0.f, 0.f};

  float4 aF0, aF1;
  uint4 aR;
  uint4 bR[BSTEP];

  auto loadA = [&](int k0) {
    const AT* src = A + (size_t)(m0 + arow) * lda + k0 + ak8 * 8;
    if constexpr (std::is_same_v<AT, float>) {
      aF0 = *(const float4*)src;
      aF1 = *(const float4*)(src + 4);
    } else {
      aR = *(const uint4*)src;
    }
  };
  auto loadB = [&](int k0) {
#pragma unroll
    for (int i = 0; i < BSTEP; ++i) {
      int s = tid + i * 512;
      bR[i] = *(const uint4*)(WT + (size_t)(s >> 2) * 256 + k0 + (s & 3) * 8);
    }
  };
  auto writeLDS = [&](int cur) {
    ushort* Ab = Asb + cur * (128 * 32);
    ushort* Bb = Bsb + cur * (BN * 32);
    uint4 pk;
    if constexpr (std::is_same_v<AT, float>)
      pk = make_uint4(pkh(aF0.x, aF0.y), pkh(aF0.z, aF0.w),
                      pkh(aF1.x, aF1.y), pkh(aF1.z, aF1.w));
    else
      pk = aR;
    *(uint4*)&Ab[swz8(arow, ak8)] = pk;
#pragma unroll
    for (int i = 0; i < BSTEP; ++i) {
      int s = tid + i * 512;
      *(uint4*)&Bb[swz8(s >> 2, s & 3)] = bR[i];
    }
  };

  loadA(0);
  loadB(0);
#pragma unroll
  for (int ks = 0; ks < 8; ++ks) {
    const int cur = ks & 1;
    writeLDS(cur);
    __syncthreads();
    if (ks < 7) {  // prefetch AFTER barrier: overlaps ds_read + MFMA below
      loadA((ks + 1) * 32);
      loadB((ks + 1) * 32);
    }
    const ushort* Ab = Asb + cur * (128 * 32);
    const ushort* Bb = Bsb + cur * (BN * 32);
    half8 af[4], bfr[NI];
#pragma unroll
    for (int mi = 0; mi < 4; ++mi)
      af[mi] = *(const half8*)&Ab[swz8(wm * 64 + mi * 16 + lr, lk)];
#pragma unroll
    for (int ni = 0; ni < NI; ++ni)
      bfr[ni] = *(const half8*)&Bb[swz8(wn * WN + ni * 16 + lr, lk)];
#pragma unroll
    for (int mi = 0; mi < 4; ++mi)
#pragma unroll
      for (int ni = 0; ni < NI; ++ni)
        acc[mi][ni] = __builtin_amdgcn_mfma_f32_16x16x32_f16(
            af[mi], bfr[ni], acc[mi][ni], 0, 0, 0);
  }
#pragma unroll
  for (int mi = 0; mi < 4; ++mi) {
#pragma unroll
    for (int ni = 0; ni < NI; ++ni) {
      int col = wn * WN + ni * 16 + lr;
      float bs;
      if constexpr (SPLIT)
        bs = (col < 256) ? bias[col] : bias2[col - 256];
      else
        bs = bias[col];
      int row = m0 + wm * 64 + mi * 16 + lk * 4;
#pragma unroll
      for (int r = 0; r < 4; ++r) {
        float v = acc[mi][ni][r] + bs;
        if constexpr (SPLIT) {
          if (col < 256)
            ((ushort*)Cout)[(size_t)(row + r) * 256 + col] = h16(v);
          else
            C2[(size_t)(row + r) * 128 + col - 256] = h16(v);
        } else if constexpr (std::is_same_v<OT, ushort>) {
          Cout[(size_t)(row + r) * ldc + col] = h16(v);
        } else {
          Cout[(size_t)(row + r) * ldc + col] = v;
        }
      }
    }
  }
}

// ---- front: blocks 0..339 -> value GEMM, 340..679 -> offsets+logits GEMM ---
__global__ __launch_bounds__(512) void gemm_front(
    const float* __restrict__ inpf, const ushort* __restrict__ WTv,
    const float* __restrict__ bval, ushort* __restrict__ value16,
    const float* __restrict__ query, const ushort* __restrict__ WTol,
    const float* __restrict__ boff, const float* __restrict__ battn,
    ushort* __restrict__ off16, ushort* __restrict__ logit16) {
  __shared__ ushort Asb[2 * 128 * 32];
  __shared__ ushort Bsb[2 * 384 * 32];
  int bid = blockIdx.x;
  if (bid < 340) {
    gemm_body<256, false, float, ushort>(inpf, 256, WTv, bval, nullptr,
                                         value16, 256, nullptr, bid, Asb, Bsb);
  } else {
    gemm_body<384, true, float, ushort>(query, 256, WTol, boff, battn, off16,
                                        256, logit16, bid - 340, Asb, Bsb);
  }
}

__global__ __launch_bounds__(512) void gemm_out(
    const ushort* __restrict__ midb, const ushort* __restrict__ WTu,
    const float* __restrict__ bout, float* __restrict__ outp) {
  __shared__ ushort Asb[2 * 128 * 32];
  __shared__ ushort Bsb[2 * 256 * 32];
  gemm_body<256, false, ushort, float>(midb, 512, WTu, bout, nullptr, outp,
                                       256, nullptr, blockIdx.x, Asb, Bsb);
}

// -------- prep: all weight transposes (f32 [K][N] -> f16 [N][256]) ----------
__global__ __launch_bounds__(256) void wt_cvt_all(
    const float* __restrict__ Wval, const float* __restrict__ Woff,
    const float* __restrict__ Wattn, const float* __restrict__ Wout,
    ushort* __restrict__ WTv, ushort* __restrict__ WTol,
    ushort* __restrict__ WTu) {
  int i = blockIdx.x * 256 + threadIdx.x;  // < 229376
  if (i < 65536) {
    int n = i >> 8, k = i & 255;
    WTv[i] = h16(Wval[(size_t)k * 256 + n]);
  } else if (i < 163840) {
    int j = i - 65536;
    int n = j >> 8, k = j & 255;
    float s = (n < 256) ? Woff[(size_t)k * 256 + n] : Wattn[(size_t)k * 128 + n - 256];
    WTol[j] = h16(s);
  } else {
    int j = i - 163840;
    int n = j >> 8, k = j & 255;
    WTu[j] = h16(Wout[(size_t)k * 256 + n]);
  }
}

// ------------- sampler: XCD-pinned (batch, head-pair) groups ----------------
// block = 256 thr; grp = blockIdx&7 -> (batch, head-pair); 32 queries/block.
// Task record (16B): {byte-offset of corner00 (incl. level+head+lane-uniform),
//                     dxB|dyB deltas (disjoint bits), packed w00w10, w01w11}.
__global__ __launch_bounds__(256, 4) void msda_sample(
    const ushort* __restrict__ off16,   // [M][256] f16
    const ushort* __restrict__ logit16, // [M][128] f16
    const float* __restrict__ refpts,   // [M][4][2]
    const ushort* __restrict__ value,   // [B][LEN][256] f16
    ushort* __restrict__ midb) {        // f16, row r at midb + r*512
  __shared__ float prs[64][16];        // 4 KB
  __shared__ float refs[32][4][2];     // 1 KB
  __shared__ uint4 trec[1024];         // 16 KB

  const int bid = blockIdx.x;
  const int grp = bid & 7;        // -> XCD (round-robin dispatch assumption)
  const int sub = bid >> 3;       // 0..679
  const int b = grp >> 2;
  const int hp = grp & 3;         // head pair: heads 2hp, 2hp+1
  const int q0 = sub * 32;
  const int tid = threadIdx.x;
  const size_t fqB = (size_t)b * LQ + q0;

  // ---- A0: refs (32q x 8 vals, 1/thread) + softmax for 64 (q, h') pairs ----
  {
    int q = tid >> 3, r = tid & 7;
    refs[q][r >> 1][r & 1] = refpts[(fqB + q) * 8 + r];
  }
  if (tid < 64) {
    int q = tid >> 1, hh = tid & 1;
    int h = hp * 2 + hh;
    const uint4* lp = (const uint4*)(logit16 + (fqB + q) * 128 + h * 16);
    uint4 p0 = lp[0], p1 = lp[1];
    float v[16] = {hlo(p0.x), hhi(p0.x), hlo(p0.y), hhi(p0.y),
                   hlo(p0.z), hhi(p0.z), hlo(p0.w), hhi(p0.w),
                   hlo(p1.x), hhi(p1.x), hlo(p1.y), hhi(p1.y),
                   hlo(p1.z), hhi(p1.z), hlo(p1.w), hhi(p1.w)};
    float m = v[0];
#pragma unroll
    for (int i = 1; i < 16; ++i) m = fmaxf(m, v[i]);
    float s = 0.f;
#pragma unroll
    for (int i = 0; i < 16; ++i) { v[i] = __expf(v[i] - m); s += v[i]; }
    float inv = 1.0f / s;
#pragma unroll
    for (int i = 0; i < 16; ++i) prs[tid][i] = v[i] * inv;
  }
  __syncthreads();

  // ---- A2: 1024 tasks (q 0..31, h' 0..1, lp 0..15), 4 per thread ----
#pragma unroll
  for (int i = 0; i < 4; ++i) {
    int t = tid + i * 256;
    int q = t >> 5;
    int hh = (t >> 4) & 1;
    int lp_ = t & 15;
    int lvl = lp_ >> 2;
    int h = hp * 2 + hh;
    uint op = ((const uint*)off16)[(fqB + q) * 128 + h * 16 + lp_];
    float ox = hlo(op), oy = hhi(op);
    float aw = prs[q * 2 + hh][lp_];
    float rx = refs[q][lvl][0], ry = refs[q][lvl][1];
    int Wl = 128 >> lvl;
    int st = (lvl == 0) ? 0 : ((lvl == 1) ? 16384 : ((lvl == 2) ? 20480 : 21504));
    float fW = (float)Wl;
    float invW = 1.0f / fW;
    float x = (rx + ox * invW) * fW - 0.5f;
    float y = (ry + oy * invW) * fW - 0.5f;
    float x0f = floorf(x), y0f = floorf(y);
    float wx1 = x - x0f, wy1 = y - y0f;
    float wx0 = 1.f - wx1, wy0 = 1.f - wy1;
    int x0 = (int)x0f, y0 = (int)y0f;
    int x1 = x0 + 1, y1 = y0 + 1;
    bool vx0 = (x0 >= 0) & (x0 < Wl), vx1 = (x1 >= 0) & (x1 < Wl);
    bool vy0 = (y0 >= 0) & (y0 < Wl), vy1 = (y1 >= 0) & (y1 < Wl);
    int xc0 = min(max(x0, 0), Wl - 1), xc1 = min(max(x1, 0), Wl - 1);
    int yc0 = min(max(y0, 0), Wl - 1), yc1 = min(max(y1, 0), Wl - 1);
    int g16 = t >> 4;
    int slot = (t & ~15) | ((t + g16) & 15);
    float w00 = (vx0 && vy0) ? wx0 * wy0 * aw : 0.f;
    float w10 = (vx1 && vy0) ? wx1 * wy0 * aw : 0.f;
    float w01 = (vx0 && vy1) ? wx0 * wy1 * aw : 0.f;
    float w11 = (vx1 && vy1) ? wx1 * wy1 * aw : 0.f;
    // byte offset of corner (yc0, xc0) for this head/level (ushort*2)
    uint ixB = (uint)((((st + yc0 * Wl + xc0) * 256) + h * 32) * 2);
    // dxB in {0, 512}; dyB in {0, 65536 >> lvl} -- disjoint bit ranges
    uint dxy = (uint)((xc1 - xc0) * 512) | (uint)((yc1 - yc0) * Wl * 512);
    trec[slot] = make_uint4(ixB, dxy, pkh(w00, w10), pkh(w01, w11));
  }
  __syncthreads();

  // ---- B: gather. 4 lanes per (q,h'); lane owns 8 dims (16B f16 loads) ----
  // Depth-2 software pipeline: records 4 tasks ahead, loads 2 tasks ahead.
  const int g = tid >> 2;
  const int dl = tid & 3;
  const uint dlB = (uint)dl * 16u;
  const char* vb0c = (const char*)(value + (size_t)b * (LEN * 256));
  const int tb = g * 16;
  float a0 = 0.f, a1 = 0.f, a2 = 0.f, a3 = 0.f;
  float a4 = 0.f, a5 = 0.f, a6 = 0.f, a7 = 0.f;

#define FMAMIX(ACC, WP, U, OPSEL) \
  asm("v_fma_mix_f32 %0, %1, %2, %0 " OPSEL : "+v"(ACC) : "v"(WP), "v"(U))
#define CORNER(U, WPW, WS)                                              \
  FMAMIX(a0, WPW, (U).x, "op_sel:[" WS ",0,0] op_sel_hi:[1,1,0]");      \
  FMAMIX(a1, WPW, (U).x, "op_sel:[" WS ",1,0] op_sel_hi:[1,1,0]");      \
  FMAMIX(a2, WPW, (U).y, "op_sel:[" WS ",0,0] op_sel_hi:[1,1,0]");      \
  FMAMIX(a3, WPW, (U).y, "op_sel:[" WS ",1,0] op_sel_hi:[1,1,0]");      \
  FMAMIX(a4, WPW, (U).z, "op_sel:[" WS ",0,0] op_sel_hi:[1,1,0]");      \
  FMAMIX(a5, WPW, (U).z, "op_sel:[" WS ",1,0] op_sel_hi:[1,1,0]");      \
  FMAMIX(a6, WPW, (U).w, "op_sel:[" WS ",0,0] op_sel_hi:[1,1,0]");      \
  FMAMIX(a7, WPW, (U).w, "op_sel:[" WS ",1,0] op_sel_hi:[1,1,0]")

#define LDREC(R, T) { (R) = trec[tb + (((T) + g) & 15)]; }
#define ISSUE(R, S) {                                       \
    uint dx_ = (R).y & 0x3ffu;                              \
    uint dy_ = (R).y - dx_;                                 \
    uint o0_ = (R).x + dlB;                                 \
    uint o2_ = o0_ + dy_;                                   \
    S[0] = *(const uint4*)(vb0c + o0_);                     \
    S[1] = *(const uint4*)(vb0c + (o0_ + dx_));             \
    S[2] = *(const uint4*)(vb0c + o2_);                     \
    S[3] = *(const uint4*)(vb0c + (o2_ + dx_)); }
#define ACCUM(R, S)                                         \
  CORNER(S[0], (R).z, "0"); CORNER(S[1], (R).z, "1");       \
  CORNER(S[2], (R).w, "0"); CORNER(S[3], (R).w, "1")

  uint4 rec[5];
  uint4 ld[3][4];
  LDREC(rec[0], 0); LDREC(rec[1], 1); LDREC(rec[2], 2); LDREC(rec[3], 3);
  ISSUE(rec[0], ld[0]);
  ISSUE(rec[1], ld[1]);
#pragma unroll
  for (int t = 0; t < 16; ++t) {
    if (t < 14) { ISSUE(rec[(t + 2) % 5], ld[(t + 2) % 3]); }
    if (t < 12) { LDREC(rec[(t + 4) % 5], t + 4); }
    ACCUM(rec[t % 5], ld[t % 3]);
  }
#undef ACCUM
#undef ISSUE
#undef LDREC
#undef CORNER
#undef FMAMIX

  const int q = g >> 1, h = hp * 2 + (g & 1);
  ushort* mp = midb + (fqB + q) * 512 + h * 32 + dl * 8;
  *(uint4*)mp = make_uint4(pkh(a0, a1), pkh(a2, a3), pkh(a4, a5), pkh(a6, a7));
}

extern "C" void kernel_launch(void* const* d_in, const int* in_sizes, int n_in,
                              void* d_out, int out_size, void* d_ws,
                              size_t ws_size, hipStream_t stream) {
  (void)in_sizes; (void)n_in; (void)out_size; (void)ws_size;
  const float* query = (const float*)d_in[0];
  const float* refp  = (const float*)d_in[1];
  const float* inpf  = (const float*)d_in[2];
  const float* Woff  = (const float*)d_in[5];
  const float* boff  = (const float*)d_in[6];
  const float* Wattn = (const float*)d_in[7];
  const float* battn = (const float*)d_in[8];
  const float* Wval  = (const float*)d_in[9];
  const float* bval  = (const float*)d_in[10];
  const float* Wout  = (const float*)d_in[11];
  const float* bout  = (const float*)d_in[12];

  // ws: value16 22.3MB | off16 22.3MB | logit16 11.1MB | WT f16 ~0.45MB
  ushort* value16 = (ushort*)d_ws;
  ushort* off16   = value16 + (size_t)MROWS * 256;
  ushort* logit16 = off16 + (size_t)MROWS * 256;
  ushort* WTv     = logit16 + (size_t)MROWS * 128;
  ushort* WTol    = WTv + 65536;   // [384][256]
  ushort* WTu     = WTol + 98304;

  ushort* midb = (ushort*)d_out;   // mid f16 in-place per row (stride 512)

  wt_cvt_all<<<896, 256, 0, stream>>>(Wval, Woff, Wattn, Wout, WTv, WTol, WTu);

  gemm_front<<<680, 512, 0, stream>>>(inpf, WTv, bval, value16, query, WTol,
                                      boff, battn, off16, logit16);

  msda_sample<<<MROWS / 8, 256, 0, stream>>>(off16, logit16, refp, value16,
                                             midb);

  gemm_out<<<MROWS / 128, 512, 0, stream>>>(midb, WTu, bout, (float*)d_out);
}

// Round 2
// 144.711 us; speedup vs baseline: 1.0125x; 1.0125x over previous
//
#include <hip/hip_runtime.h>
#include <hip/hip_fp16.h>
#include <type_traits>

#define LQ 21760
#define MROWS 43520
#define LEN 21760

typedef __attribute__((ext_vector_type(8))) _Float16 half8;
typedef __attribute__((ext_vector_type(4))) float f32x4;

__device__ __forceinline__ uint pkh(float a, float b) {
  auto v = __builtin_amdgcn_cvt_pkrtz(a, b);
  return __builtin_bit_cast(uint, v);
}
__device__ __forceinline__ ushort h16(float x) {
  return __half_as_ushort(__float2half(x));
}
__device__ __forceinline__ float hlo(uint u) {
  return __half2float(__ushort_as_half((ushort)(u & 0xffffu)));
}
__device__ __forceinline__ float hhi(uint u) {
  return __half2float(__ushort_as_half((ushort)(u >> 16)));
}

// ushort index of the 16B slot for (row, k8) with XOR swizzle (<=2-way banks)
__device__ __forceinline__ int swz8(int row, int k8) {
  return row * 32 + ((k8 ^ (row & 3) ^ ((row >> 2) & 3)) << 3);
}

// ---- f16 MFMA GEMM body, double-buffered LDS, 1 barrier per K-step --------
// C[128, BN] = A[128, K=256] @ WT^T + bias. 512 thr = 8 waves (2M x 4N).
template <int BN, bool SPLIT, typename AT, typename OT>
__device__ __forceinline__ void gemm_body(
    const AT* __restrict__ A, int lda, const ushort* __restrict__ WT,
    const float* __restrict__ bias, const float* __restrict__ bias2,
    OT* __restrict__ Cout, int ldc, ushort* __restrict__ C2, int mblk,
    ushort* Asb, ushort* Bsb) {
  constexpr int WN = BN / 4;
  constexpr int NI = WN / 16;
  constexpr int BSTEP = (BN * 4) / 512;
  const int tid = threadIdx.x;
  const int m0 = mblk * 128;
  const int w = tid >> 6, wm = w >> 2, wn = w & 3;
  const int l = tid & 63, lr = l & 15, lk = l >> 4;
  const int arow = tid >> 2, ak8 = tid & 3;

  f32x4 acc[4][NI];
#pragma unroll
  for (int mi = 0; mi < 4; ++mi)
#pragma unroll
    for (int ni = 0; ni < NI; ++ni) acc[mi][ni] = {0.f, 0.f, 0.f, 0.f};

  float4 aF0, aF1;
  uint4 aR;
  uint4 bR[BSTEP];

  auto loadA = [&](int k0) {
    const AT* src = A + (size_t)(m0 + arow) * lda + k0 + ak8 * 8;
    if constexpr (std::is_same_v<AT, float>) {
      aF0 = *(const float4*)src;
      aF1 = *(const float4*)(src + 4);
    } else {
      aR = *(const uint4*)src;
    }
  };
  auto loadB = [&](int k0) {
#pragma unroll
    for (int i = 0; i < BSTEP; ++i) {
      int s = tid + i * 512;
      bR[i] = *(const uint4*)(WT + (size_t)(s >> 2) * 256 + k0 + (s & 3) * 8);
    }
  };
  auto writeLDS = [&](int cur) {
    ushort* Ab = Asb + cur * (128 * 32);
    ushort* Bb = Bsb + cur * (BN * 32);
    uint4 pk;
    if constexpr (std::is_same_v<AT, float>)
      pk = make_uint4(pkh(aF0.x, aF0.y), pkh(aF0.z, aF0.w),
                      pkh(aF1.x, aF1.y), pkh(aF1.z, aF1.w));
    else
      pk = aR;
    *(uint4*)&Ab[swz8(arow, ak8)] = pk;
#pragma unroll
    for (int i = 0; i < BSTEP; ++i) {
      int s = tid + i * 512;
      *(uint4*)&Bb[swz8(s >> 2, s & 3)] = bR[i];
    }
  };

  loadA(0);
  loadB(0);
#pragma unroll
  for (int ks = 0; ks < 8; ++ks) {
    const int cur = ks & 1;
    writeLDS(cur);
    __syncthreads();
    if (ks < 7) {  // prefetch AFTER barrier: overlaps ds_read + MFMA below
      loadA((ks + 1) * 32);
      loadB((ks + 1) * 32);
    }
    const ushort* Ab = Asb + cur * (128 * 32);
    const ushort* Bb = Bsb + cur * (BN * 32);
    half8 af[4], bfr[NI];
#pragma unroll
    for (int mi = 0; mi < 4; ++mi)
      af[mi] = *(const half8*)&Ab[swz8(wm * 64 + mi * 16 + lr, lk)];
#pragma unroll
    for (int ni = 0; ni < NI; ++ni)
      bfr[ni] = *(const half8*)&Bb[swz8(wn * WN + ni * 16 + lr, lk)];
#pragma unroll
    for (int mi = 0; mi < 4; ++mi)
#pragma unroll
      for (int ni = 0; ni < NI; ++ni)
        acc[mi][ni] = __builtin_amdgcn_mfma_f32_16x16x32_f16(
            af[mi], bfr[ni], acc[mi][ni], 0, 0, 0);
  }
#pragma unroll
  for (int mi = 0; mi < 4; ++mi) {
#pragma unroll
    for (int ni = 0; ni < NI; ++ni) {
      int col = wn * WN + ni * 16 + lr;
      float bs;
      if constexpr (SPLIT)
        bs = (col < 256) ? bias[col] : bias2[col - 256];
      else
        bs = bias[col];
      int row = m0 + wm * 64 + mi * 16 + lk * 4;
#pragma unroll
      for (int r = 0; r < 4; ++r) {
        float v = acc[mi][ni][r] + bs;
        if constexpr (SPLIT) {
          if (col < 256)
            ((ushort*)Cout)[(size_t)(row + r) * 256 + col] = h16(v);
          else
            C2[(size_t)(row + r) * 128 + col - 256] = h16(v);
        } else if constexpr (std::is_same_v<OT, ushort>) {
          Cout[(size_t)(row + r) * ldc + col] = h16(v);
        } else {
          Cout[(size_t)(row + r) * ldc + col] = v;
        }
      }
    }
  }
}

// ---- front: blocks 0..339 -> value GEMM, 340..679 -> offsets+logits GEMM ---
__global__ __launch_bounds__(512) void gemm_front(
    const float* __restrict__ inpf, const ushort* __restrict__ WTv,
    const float* __restrict__ bval, ushort* __restrict__ value16,
    const float* __restrict__ query, const ushort* __restrict__ WTol,
    const float* __restrict__ boff, const float* __restrict__ battn,
    ushort* __restrict__ off16, ushort* __restrict__ logit16) {
  __shared__ ushort Asb[2 * 128 * 32];
  __shared__ ushort Bsb[2 * 384 * 32];
  int bid = blockIdx.x;
  if (bid < 340) {
    gemm_body<256, false, float, ushort>(inpf, 256, WTv, bval, nullptr,
                                         value16, 256, nullptr, bid, Asb, Bsb);
  } else {
    gemm_body<384, true, float, ushort>(query, 256, WTol, boff, battn, off16,
                                        256, logit16, bid - 340, Asb, Bsb);
  }
}

__global__ __launch_bounds__(512) void gemm_out(
    const ushort* __restrict__ midb, const ushort* __restrict__ WTu,
    const float* __restrict__ bout, float* __restrict__ outp) {
  __shared__ ushort Asb[2 * 128 * 32];
  __shared__ ushort Bsb[2 * 256 * 32];
  gemm_body<256, false, ushort, float>(midb, 512, WTu, bout, nullptr, outp,
                                       256, nullptr, blockIdx.x, Asb, Bsb);
}

// -------- prep: all weight transposes (f32 [K][N] -> f16 [N][256]) ----------
__global__ __launch_bounds__(256) void wt_cvt_all(
    const float* __restrict__ Wval, const float* __restrict__ Woff,
    const float* __restrict__ Wattn, const float* __restrict__ Wout,
    ushort* __restrict__ WTv, ushort* __restrict__ WTol,
    ushort* __restrict__ WTu) {
  int i = blockIdx.x * 256 + threadIdx.x;  // < 229376
  if (i < 65536) {
    int n = i >> 8, k = i & 255;
    WTv[i] = h16(Wval[(size_t)k * 256 + n]);
  } else if (i < 163840) {
    int j = i - 65536;
    int n = j >> 8, k = j & 255;
    float s = (n < 256) ? Woff[(size_t)k * 256 + n] : Wattn[(size_t)k * 128 + n - 256];
    WTol[j] = h16(s);
  } else {
    int j = i - 163840;
    int n = j >> 8, k = j & 255;
    WTu[j] = h16(Wout[(size_t)k * 256 + n]);
  }
}

// ------------- sampler: XCD-pinned (batch, head-pair) groups ----------------
// block = 256 thr; grp = blockIdx&7 -> (batch, head-pair); 32 queries/block.
// NOTE: LDS kept at 29,696 B (5 blocks/CU target) deliberately — shrinking it
// raises the compiler's occupancy target and makes the allocator clamp VGPRs,
// destroying the gather pipeline (measured round-1: VGPR 40, +13 us).
__global__ __launch_bounds__(256) void msda_sample(
    const ushort* __restrict__ off16,   // [M][256] f16
    const ushort* __restrict__ logit16, // [M][128] f16
    const float* __restrict__ refpts,   // [M][4][2]
    const ushort* __restrict__ value,   // [B][LEN][256] f16
    ushort* __restrict__ midb) {        // f16, row r at midb + r*512
  __shared__ float prs[64][16];   // 4 KB
  __shared__ float refs[32][4][2];
  __shared__ int tix[1024][4];    // 16 KB
  __shared__ uint twp[1024][2];   // 8 KB

  const int bid = blockIdx.x;
  const int grp = bid & 7;        // -> XCD (round-robin dispatch assumption)
  const int sub = bid >> 3;       // 0..679
  const int b = grp >> 2;
  const int hp = grp & 3;         // head pair: heads 2hp, 2hp+1
  const int q0 = sub * 32;
  const int tid = threadIdx.x;
  const size_t fqB = (size_t)b * LQ + q0;

  // ---- A0: refs (32q x 8 vals, 1/thread) + softmax for 64 (q, h') pairs ----
  {
    int q = tid >> 3, r = tid & 7;
    refs[q][r >> 1][r & 1] = refpts[(fqB + q) * 8 + r];
  }
  if (tid < 64) {
    int q = tid >> 1, hh = tid & 1;
    int h = hp * 2 + hh;
    const uint4* lp = (const uint4*)(logit16 + (fqB + q) * 128 + h * 16);
    uint4 p0 = lp[0], p1 = lp[1];
    float v[16] = {hlo(p0.x), hhi(p0.x), hlo(p0.y), hhi(p0.y),
                   hlo(p0.z), hhi(p0.z), hlo(p0.w), hhi(p0.w),
                   hlo(p1.x), hhi(p1.x), hlo(p1.y), hhi(p1.y),
                   hlo(p1.z), hhi(p1.z), hlo(p1.w), hhi(p1.w)};
    float m = v[0];
#pragma unroll
    for (int i = 1; i < 16; ++i) m = fmaxf(m, v[i]);
    float s = 0.f;
#pragma unroll
    for (int i = 0; i < 16; ++i) { v[i] = __expf(v[i] - m); s += v[i]; }
    float inv = 1.0f / s;
#pragma unroll
    for (int i = 0; i < 16; ++i) prs[tid][i] = v[i] * inv;
  }
  __syncthreads();

  // ---- A2: 1024 tasks (q 0..31, h' 0..1, lp 0..15), 4 per thread ----
#pragma unroll
  for (int i = 0; i < 4; ++i) {
    int t = tid + i * 256;
    int q = t >> 5;
    int hh = (t >> 4) & 1;
    int lp_ = t & 15;
    int lvl = lp_ >> 2;
    int h = hp * 2 + hh;
    uint op = ((const uint*)off16)[(fqB + q) * 128 + h * 16 + lp_];
    float ox = hlo(op), oy = hhi(op);
    float aw = prs[q * 2 + hh][lp_];
    float rx = refs[q][lvl][0], ry = refs[q][lvl][1];
    int Wl = 128 >> lvl;
    int st = (lvl == 0) ? 0 : ((lvl == 1) ? 16384 : ((lvl == 2) ? 20480 : 21504));
    float fW = (float)Wl;
    float invW = 1.0f / fW;
    float x = (rx + ox * invW) * fW - 0.5f;
    float y = (ry + oy * invW) * fW - 0.5f;
    float x0f = floorf(x), y0f = floorf(y);
    float wx1 = x - x0f, wy1 = y - y0f;
    float wx0 = 1.f - wx1, wy0 = 1.f - wy1;
    int x0 = (int)x0f, y0 = (int)y0f;
    int x1 = x0 + 1, y1 = y0 + 1;
    bool vx0 = (x0 >= 0) & (x0 < Wl), vx1 = (x1 >= 0) & (x1 < Wl);
    bool vy0 = (y0 >= 0) & (y0 < Wl), vy1 = (y1 >= 0) & (y1 < Wl);
    int xc0 = min(max(x0, 0), Wl - 1), xc1 = min(max(x1, 0), Wl - 1);
    int yc0 = min(max(y0, 0), Wl - 1), yc1 = min(max(y1, 0), Wl - 1);
    int base = st * 256 + h * 32;
    int g16 = t >> 4;
    int slot = (t & ~15) | ((t + g16) & 15);
    float w00 = (vx0 && vy0) ? wx0 * wy0 * aw : 0.f;
    float w10 = (vx1 && vy0) ? wx1 * wy0 * aw : 0.f;
    float w01 = (vx0 && vy1) ? wx0 * wy1 * aw : 0.f;
    float w11 = (vx1 && vy1) ? wx1 * wy1 * aw : 0.f;
    tix[slot][0] = base + (yc0 * Wl + xc0) * 256;
    tix[slot][1] = base + (yc0 * Wl + xc1) * 256;
    tix[slot][2] = base + (yc1 * Wl + xc0) * 256;
    tix[slot][3] = base + (yc1 * Wl + xc1) * 256;
    twp[slot][0] = pkh(w00, w10);
    twp[slot][1] = pkh(w01, w11);
  }
  __syncthreads();

  // ---- B: gather. 4 lanes per (q,h'); lane owns 8 dims (16B f16 loads) ----
  // Depth-1 two-task alternating pipeline: while ACCUM of task A runs, the
  // 4 gathers of task B are in flight (<=8 loads outstanding; 32 VGPR payload).
  const int g = tid >> 2;
  const int dl = tid & 3;
  const ushort* vb = value + (size_t)b * LEN * 256 + dl * 8;
  float a0 = 0.f, a1 = 0.f, a2 = 0.f, a3 = 0.f;
  float a4 = 0.f, a5 = 0.f, a6 = 0.f, a7 = 0.f;
  const int tb = g * 16;

#define FMAMIX(ACC, WP, U, OPSEL) \
  asm("v_fma_mix_f32 %0, %1, %2, %0 " OPSEL : "+v"(ACC) : "v"(WP), "v"(U))
#define CORNER(U, WPW, WS)                                              \
  FMAMIX(a0, WPW, (U).x, "op_sel:[" WS ",0,0] op_sel_hi:[1,1,0]");      \
  FMAMIX(a1, WPW, (U).x, "op_sel:[" WS ",1,0] op_sel_hi:[1,1,0]");      \
  FMAMIX(a2, WPW, (U).y, "op_sel:[" WS ",0,0] op_sel_hi:[1,1,0]");      \
  FMAMIX(a3, WPW, (U).y, "op_sel:[" WS ",1,0] op_sel_hi:[1,1,0]");      \
  FMAMIX(a4, WPW, (U).z, "op_sel:[" WS ",0,0] op_sel_hi:[1,1,0]");      \
  FMAMIX(a5, WPW, (U).z, "op_sel:[" WS ",1,0] op_sel_hi:[1,1,0]");      \
  FMAMIX(a6, WPW, (U).w, "op_sel:[" WS ",0,0] op_sel_hi:[1,1,0]");      \
  FMAMIX(a7, WPW, (U).w, "op_sel:[" WS ",1,0] op_sel_hi:[1,1,0]")

#define LDREC(T, IX, WP) {                                  \
    int slot_ = tb + (((T) + g) & 15);                      \
    (IX) = *(const int4*)&tix[slot_][0];                    \
    (WP) = *(const uint2*)&twp[slot_][0]; }
#define ISSUE(IX, U) {                                      \
    U[0] = *(const uint4*)(vb + (IX).x);                    \
    U[1] = *(const uint4*)(vb + (IX).y);                    \
    U[2] = *(const uint4*)(vb + (IX).z);                    \
    U[3] = *(const uint4*)(vb + (IX).w); }
#define ACCUM(U, WP)                                        \
  CORNER(U[0], (WP).x, "0"); CORNER(U[1], (WP).x, "1");     \
  CORNER(U[2], (WP).y, "0"); CORNER(U[3], (WP).y, "1")

  int4 ixA, ixB;
  uint2 wpA, wpB;
  uint4 uA[4], uB[4];
  LDREC(0, ixA, wpA);
  ISSUE(ixA, uA);
#pragma unroll
  for (int t = 0; t < 16; t += 2) {
    LDREC(t + 1, ixB, wpB);
    ISSUE(ixB, uB);
    ACCUM(uA, wpA);                    // waits uA; uB stays in flight
    if (t + 2 < 16) {
      LDREC(t + 2, ixA, wpA);
      ISSUE(ixA, uA);
    }
    ACCUM(uB, wpB);                    // waits uB; next uA stays in flight
  }
#undef ACCUM
#undef ISSUE
#undef LDREC
#undef CORNER
#undef FMAMIX

  const int q = g >> 1, h = hp * 2 + (g & 1);
  ushort* mp = midb + (fqB + q) * 512 + h * 32 + dl * 8;
  *(uint4*)mp = make_uint4(pkh(a0, a1), pkh(a2, a3), pkh(a4, a5), pkh(a6, a7));
}

extern "C" void kernel_launch(void* const* d_in, const int* in_sizes, int n_in,
                              void* d_out, int out_size, void* d_ws,
                              size_t ws_size, hipStream_t stream) {
  (void)in_sizes; (void)n_in; (void)out_size; (void)ws_size;
  const float* query = (const float*)d_in[0];
  const float* refp  = (const float*)d_in[1];
  const float* inpf  = (const float*)d_in[2];
  const float* Woff  = (const float*)d_in[5];
  const float* boff  = (const float*)d_in[6];
  const float* Wattn = (const float*)d_in[7];
  const float* battn = (const float*)d_in[8];
  const float* Wval  = (const float*)d_in[9];
  const float* bval  = (const float*)d_in[10];
  const float* Wout  = (const float*)d_in[11];
  const float* bout  = (const float*)d_in[12];

  // ws: value16 22.3MB | off16 22.3MB | logit16 11.1MB | WT f16 ~0.45MB
  ushort* value16 = (ushort*)d_ws;
  ushort* off16   = value16 + (size_t)MROWS * 256;
  ushort* logit16 = off16 + (size_t)MROWS * 256;
  ushort* WTv     = logit16 + (size_t)MROWS * 128;
  ushort* WTol    = WTv + 65536;   // [384][256]
  ushort* WTu     = WTol + 98304;

  ushort* midb = (ushort*)d_out;   // mid f16 in-place per row (stride 512)

  wt_cvt_all<<<896, 256, 0, stream>>>(Wval, Woff, Wattn, Wout, WTv, WTol, WTu);

  gemm_front<<<680, 512, 0, stream>>>(inpf, WTv, bval, value16, query, WTol,
                                      boff, battn, off16, logit16);

  msda_sample<<<MROWS / 8, 256, 0, stream>>>(off16, logit16, refp, value16,
                                             midb);

  gemm_out<<<MROWS / 128, 512, 0, stream>>>(midb, WTu, bout, (float*)d_out);
}

// Round 3
// 133.230 us; speedup vs baseline: 1.0997x; 1.0862x over previous
//
#include <hip/hip_runtime.h>
#include <hip/hip_fp16.h>
#include <type_traits>

#define LQ 21760
#define MROWS 43520
#define LEN 21760

typedef __attribute__((ext_vector_type(8))) _Float16 half8;
typedef __attribute__((ext_vector_type(4))) float f32x4;

__device__ __forceinline__ uint pkh(float a, float b) {
  auto v = __builtin_amdgcn_cvt_pkrtz(a, b);
  return __builtin_bit_cast(uint, v);
}
__device__ __forceinline__ ushort h16(float x) {
  return __half_as_ushort(__float2half(x));
}
__device__ __forceinline__ float hlo(uint u) {
  return __half2float(__ushort_as_half((ushort)(u & 0xffffu)));
}
__device__ __forceinline__ float hhi(uint u) {
  return __half2float(__ushort_as_half((ushort)(u >> 16)));
}

// ushort index of the 16B slot for (row, k8) with XOR swizzle (<=2-way banks)
__device__ __forceinline__ int swz8(int row, int k8) {
  return row * 32 + ((k8 ^ (row & 3) ^ ((row >> 2) & 3)) << 3);
}

// ---- f16 MFMA GEMM body, double-buffered LDS, 1 barrier per K-step --------
// C[128, BN] = A[128, K=256] @ WT^T + bias. 512 thr = 8 waves (2M x 4N).
template <int BN, bool SPLIT, typename AT, typename OT>
__device__ __forceinline__ void gemm_body(
    const AT* __restrict__ A, int lda, const ushort* __restrict__ WT,
    const float* __restrict__ bias, const float* __restrict__ bias2,
    OT* __restrict__ Cout, int ldc, ushort* __restrict__ C2, int mblk,
    ushort* Asb, ushort* Bsb) {
  constexpr int WN = BN / 4;
  constexpr int NI = WN / 16;
  constexpr int BSTEP = (BN * 4) / 512;
  const int tid = threadIdx.x;
  const int m0 = mblk * 128;
  const int w = tid >> 6, wm = w >> 2, wn = w & 3;
  const int l = tid & 63, lr = l & 15, lk = l >> 4;
  const int arow = tid >> 2, ak8 = tid & 3;

  f32x4 acc[4][NI];
#pragma unroll
  for (int mi = 0; mi < 4; ++mi)
#pragma unroll
    for (int ni = 0; ni < NI; ++ni) acc[mi][ni] = {0.f, 0.f, 0.f, 0.f};

  float4 aF0, aF1;
  uint4 aR;
  uint4 bR[BSTEP];

  auto loadA = [&](int k0) {
    const AT* src = A + (size_t)(m0 + arow) * lda + k0 + ak8 * 8;
    if constexpr (std::is_same_v<AT, float>) {
      aF0 = *(const float4*)src;
      aF1 = *(const float4*)(src + 4);
    } else {
      aR = *(const uint4*)src;
    }
  };
  auto loadB = [&](int k0) {
#pragma unroll
    for (int i = 0; i < BSTEP; ++i) {
      int s = tid + i * 512;
      bR[i] = *(const uint4*)(WT + (size_t)(s >> 2) * 256 + k0 + (s & 3) * 8);
    }
  };
  auto writeLDS = [&](int cur) {
    ushort* Ab = Asb + cur * (128 * 32);
    ushort* Bb = Bsb + cur * (BN * 32);
    uint4 pk;
    if constexpr (std::is_same_v<AT, float>)
      pk = make_uint4(pkh(aF0.x, aF0.y), pkh(aF0.z, aF0.w),
                      pkh(aF1.x, aF1.y), pkh(aF1.z, aF1.w));
    else
      pk = aR;
    *(uint4*)&Ab[swz8(arow, ak8)] = pk;
#pragma unroll
    for (int i = 0; i < BSTEP; ++i) {
      int s = tid + i * 512;
      *(uint4*)&Bb[swz8(s >> 2, s & 3)] = bR[i];
    }
  };

  loadA(0);
  loadB(0);
#pragma unroll
  for (int ks = 0; ks < 8; ++ks) {
    const int cur = ks & 1;
    writeLDS(cur);
    __syncthreads();
    if (ks < 7) {  // prefetch AFTER barrier: overlaps ds_read + MFMA below
      loadA((ks + 1) * 32);
      loadB((ks + 1) * 32);
    }
    const ushort* Ab = Asb + cur * (128 * 32);
    const ushort* Bb = Bsb + cur * (BN * 32);
    half8 af[4], bfr[NI];
#pragma unroll
    for (int mi = 0; mi < 4; ++mi)
      af[mi] = *(const half8*)&Ab[swz8(wm * 64 + mi * 16 + lr, lk)];
#pragma unroll
    for (int ni = 0; ni < NI; ++ni)
      bfr[ni] = *(const half8*)&Bb[swz8(wn * WN + ni * 16 + lr, lk)];
#pragma unroll
    for (int mi = 0; mi < 4; ++mi)
#pragma unroll
      for (int ni = 0; ni < NI; ++ni)
        acc[mi][ni] = __builtin_amdgcn_mfma_f32_16x16x32_f16(
            af[mi], bfr[ni], acc[mi][ni], 0, 0, 0);
  }
#pragma unroll
  for (int mi = 0; mi < 4; ++mi) {
#pragma unroll
    for (int ni = 0; ni < NI; ++ni) {
      int col = wn * WN + ni * 16 + lr;
      float bs;
      if constexpr (SPLIT)
        bs = (col < 256) ? bias[col] : bias2[col - 256];
      else
        bs = bias[col];
      int row = m0 + wm * 64 + mi * 16 + lk * 4;
#pragma unroll
      for (int r = 0; r < 4; ++r) {
        float v = acc[mi][ni][r] + bs;
        if constexpr (SPLIT) {
          if (col < 256)
            ((ushort*)Cout)[(size_t)(row + r) * 256 + col] = h16(v);
          else
            C2[(size_t)(row + r) * 128 + col - 256] = h16(v);
        } else if constexpr (std::is_same_v<OT, ushort>) {
          Cout[(size_t)(row + r) * ldc + col] = h16(v);
        } else {
          Cout[(size_t)(row + r) * ldc + col] = v;
        }
      }
    }
  }
}

// ---- front: blocks 0..339 -> value GEMM, 340..679 -> offsets+logits GEMM ---
__global__ __launch_bounds__(512) void gemm_front(
    const float* __restrict__ inpf, const ushort* __restrict__ WTv,
    const float* __restrict__ bval, ushort* __restrict__ value16,
    const float* __restrict__ query, const ushort* __restrict__ WTol,
    const float* __restrict__ boff, const float* __restrict__ battn,
    ushort* __restrict__ off16, ushort* __restrict__ logit16) {
  __shared__ ushort Asb[2 * 128 * 32];
  __shared__ ushort Bsb[2 * 384 * 32];
  int bid = blockIdx.x;
  if (bid < 340) {
    gemm_body<256, false, float, ushort>(inpf, 256, WTv, bval, nullptr,
                                         value16, 256, nullptr, bid, Asb, Bsb);
  } else {
    gemm_body<384, true, float, ushort>(query, 256, WTol, boff, battn, off16,
                                        256, logit16, bid - 340, Asb, Bsb);
  }
}

__global__ __launch_bounds__(512) void gemm_out(
    const ushort* __restrict__ midb, const ushort* __restrict__ WTu,
    const float* __restrict__ bout, float* __restrict__ outp) {
  __shared__ ushort Asb[2 * 128 * 32];
  __shared__ ushort Bsb[2 * 256 * 32];
  gemm_body<256, false, ushort, float>(midb, 512, WTu, bout, nullptr, outp,
                                       256, nullptr, blockIdx.x, Asb, Bsb);
}

// -------- prep: all weight transposes (f32 [K][N] -> f16 [N][256]) ----------
__global__ __launch_bounds__(256) void wt_cvt_all(
    const float* __restrict__ Wval, const float* __restrict__ Woff,
    const float* __restrict__ Wattn, const float* __restrict__ Wout,
    ushort* __restrict__ WTv, ushort* __restrict__ WTol,
    ushort* __restrict__ WTu) {
  int i = blockIdx.x * 256 + threadIdx.x;  // < 229376
  if (i < 65536) {
    int n = i >> 8, k = i & 255;
    WTv[i] = h16(Wval[(size_t)k * 256 + n]);
  } else if (i < 163840) {
    int j = i - 65536;
    int n = j >> 8, k = j & 255;
    float s = (n < 256) ? Woff[(size_t)k * 256 + n] : Wattn[(size_t)k * 128 + n - 256];
    WTol[j] = h16(s);
  } else {
    int j = i - 163840;
    int n = j >> 8, k = j & 255;
    WTu[j] = h16(Wout[(size_t)k * 256 + n]);
  }
}

// ------------- sampler: XCD-pinned (batch, head-pair) groups ----------------
// block = 256 thr; grp = blockIdx&7 -> (batch, head-pair); 32 queries/block.
// NOTE: gather-loop structure deliberately identical to the 70.9us round-0
// version — source-level load pipelining gets clamped/serialized by the
// scheduler (measured rounds 1-2: VGPR 40/44, +11-13 us). The change here is
// ALU-only: v_pk_fma_f16 (full-rate, packed) replaces v_fma_mix_f32
// (measured-slow VOP3P-mix), with f16 chunk accum promoted to f32 every
// 2 tasks (8 corners) to bound rounding error.
__global__ __launch_bounds__(256) void msda_sample(
    const ushort* __restrict__ off16,   // [M][256] f16
    const ushort* __restrict__ logit16, // [M][128] f16
    const float* __restrict__ refpts,   // [M][4][2]
    const ushort* __restrict__ value,   // [B][LEN][256] f16
    ushort* __restrict__ midb) {        // f16, row r at midb + r*512
  __shared__ float prs[64][16];   // 4 KB
  __shared__ float refs[32][4][2];
  __shared__ int tix[1024][4];    // 16 KB
  __shared__ uint twp[1024][2];   // 8 KB

  const int bid = blockIdx.x;
  const int grp = bid & 7;        // -> XCD (round-robin dispatch assumption)
  const int sub = bid >> 3;       // 0..679
  const int b = grp >> 2;
  const int hp = grp & 3;         // head pair: heads 2hp, 2hp+1
  const int q0 = sub * 32;
  const int tid = threadIdx.x;
  const size_t fqB = (size_t)b * LQ + q0;

  // ---- A0: refs (32q x 8 vals, 1/thread) + softmax for 64 (q, h') pairs ----
  {
    int q = tid >> 3, r = tid & 7;
    refs[q][r >> 1][r & 1] = refpts[(fqB + q) * 8 + r];
  }
  if (tid < 64) {
    int q = tid >> 1, hh = tid & 1;
    int h = hp * 2 + hh;
    const uint4* lp = (const uint4*)(logit16 + (fqB + q) * 128 + h * 16);
    uint4 p0 = lp[0], p1 = lp[1];
    float v[16] = {hlo(p0.x), hhi(p0.x), hlo(p0.y), hhi(p0.y),
                   hlo(p0.z), hhi(p0.z), hlo(p0.w), hhi(p0.w),
                   hlo(p1.x), hhi(p1.x), hlo(p1.y), hhi(p1.y),
                   hlo(p1.z), hhi(p1.z), hlo(p1.w), hhi(p1.w)};
    float m = v[0];
#pragma unroll
    for (int i = 1; i < 16; ++i) m = fmaxf(m, v[i]);
    float s = 0.f;
#pragma unroll
    for (int i = 0; i < 16; ++i) { v[i] = __expf(v[i] - m); s += v[i]; }
    float inv = 1.0f / s;
#pragma unroll
    for (int i = 0; i < 16; ++i) prs[tid][i] = v[i] * inv;
  }
  __syncthreads();

  // ---- A2: 1024 tasks (q 0..31, h' 0..1, lp 0..15), 4 per thread ----
#pragma unroll
  for (int i = 0; i < 4; ++i) {
    int t = tid + i * 256;
    int q = t >> 5;
    int hh = (t >> 4) & 1;
    int lp_ = t & 15;
    int lvl = lp_ >> 2;
    int h = hp * 2 + hh;
    uint op = ((const uint*)off16)[(fqB + q) * 128 + h * 16 + lp_];
    float ox = hlo(op), oy = hhi(op);
    float aw = prs[q * 2 + hh][lp_];
    float rx = refs[q][lvl][0], ry = refs[q][lvl][1];
    int Wl = 128 >> lvl;
    int st = (lvl == 0) ? 0 : ((lvl == 1) ? 16384 : ((lvl == 2) ? 20480 : 21504));
    float fW = (float)Wl;
    float invW = 1.0f / fW;
    float x = (rx + ox * invW) * fW - 0.5f;
    float y = (ry + oy * invW) * fW - 0.5f;
    float x0f = floorf(x), y0f = floorf(y);
    float wx1 = x - x0f, wy1 = y - y0f;
    float wx0 = 1.f - wx1, wy0 = 1.f - wy1;
    int x0 = (int)x0f, y0 = (int)y0f;
    int x1 = x0 + 1, y1 = y0 + 1;
    bool vx0 = (x0 >= 0) & (x0 < Wl), vx1 = (x1 >= 0) & (x1 < Wl);
    bool vy0 = (y0 >= 0) & (y0 < Wl), vy1 = (y1 >= 0) & (y1 < Wl);
    int xc0 = min(max(x0, 0), Wl - 1), xc1 = min(max(x1, 0), Wl - 1);
    int yc0 = min(max(y0, 0), Wl - 1), yc1 = min(max(y1, 0), Wl - 1);
    int base = st * 256 + h * 32;
    int g16 = t >> 4;
    int slot = (t & ~15) | ((t + g16) & 15);
    float w00 = (vx0 && vy0) ? wx0 * wy0 * aw : 0.f;
    float w10 = (vx1 && vy0) ? wx1 * wy0 * aw : 0.f;
    float w01 = (vx0 && vy1) ? wx0 * wy1 * aw : 0.f;
    float w11 = (vx1 && vy1) ? wx1 * wy1 * aw : 0.f;
    tix[slot][0] = base + (yc0 * Wl + xc0) * 256;
    tix[slot][1] = base + (yc0 * Wl + xc1) * 256;
    tix[slot][2] = base + (yc1 * Wl + xc0) * 256;
    tix[slot][3] = base + (yc1 * Wl + xc1) * 256;
    twp[slot][0] = pkh(w00, w10);
    twp[slot][1] = pkh(w01, w11);
  }
  __syncthreads();

  // ---- B: gather. 4 lanes per (q,h'); lane owns 8 dims (16B f16 loads) ----
  const int g = tid >> 2;
  const int dl = tid & 3;
  const ushort* vb = value + (size_t)b * LEN * 256 + dl * 8;
  float a0 = 0.f, a1 = 0.f, a2 = 0.f, a3 = 0.f;
  float a4 = 0.f, a5 = 0.f, a6 = 0.f, a7 = 0.f;
  uint c0 = 0u, c1 = 0u, c2 = 0u, c3 = 0u;  // f16x2 chunk accumulators
  const int tb = g * 16;

// packed f16 FMA; OS/OSH broadcast one half of the weight reg to both lanes:
//   weight = lo(WP): OS="0" OSH="0";  weight = hi(WP): OS="1" OSH="1"
#define PKC(ACC, U, WP, OS, OSH)                                        \
  asm("v_pk_fma_f16 %0, %1, %2, %0 op_sel:[0," OS ",0] op_sel_hi:[1," OSH \
      ",1]"                                                             \
      : "+v"(ACC)                                                       \
      : "v"(U), "v"(WP))
#define CORNER(U, WPW, OS, OSH)                                         \
  PKC(c0, (U).x, WPW, OS, OSH);                                         \
  PKC(c1, (U).y, WPW, OS, OSH);                                         \
  PKC(c2, (U).z, WPW, OS, OSH);                                         \
  PKC(c3, (U).w, WPW, OS, OSH)
// promote f16x2 chunk into two f32 accumulators, then reset chunk
#define PROMO1(ALO, AHI, C)                                             \
  asm("v_fma_mix_f32 %0, 1.0, %1, %0 op_sel:[0,0,0] op_sel_hi:[0,1,0]"  \
      : "+v"(ALO) : "v"(C));                                            \
  asm("v_fma_mix_f32 %0, 1.0, %1, %0 op_sel:[0,1,0] op_sel_hi:[0,1,0]"  \
      : "+v"(AHI) : "v"(C));                                            \
  C = 0u;

#pragma unroll 4
  for (int t = 0; t < 16; ++t) {
    int slot = tb + ((t + g) & 15);
    int4 ix = *(const int4*)&tix[slot][0];
    uint2 wp = *(const uint2*)&twp[slot][0];
    uint4 u0 = *(const uint4*)(vb + ix.x);
    uint4 u1 = *(const uint4*)(vb + ix.y);
    uint4 u2 = *(const uint4*)(vb + ix.z);
    uint4 u3 = *(const uint4*)(vb + ix.w);
    CORNER(u0, wp.x, "0", "0");
    CORNER(u1, wp.x, "1", "1");
    CORNER(u2, wp.y, "0", "0");
    CORNER(u3, wp.y, "1", "1");
    if ((t & 1) == 1) {  // promote every 2 tasks (8 corners) -> f32
      PROMO1(a0, a1, c0);
      PROMO1(a2, a3, c1);
      PROMO1(a4, a5, c2);
      PROMO1(a6, a7, c3);
    }
  }
#undef PROMO1
#undef CORNER
#undef PKC

  const int q = g >> 1, h = hp * 2 + (g & 1);
  ushort* mp = midb + (fqB + q) * 512 + h * 32 + dl * 8;
  *(uint4*)mp = make_uint4(pkh(a0, a1), pkh(a2, a3), pkh(a4, a5), pkh(a6, a7));
}

extern "C" void kernel_launch(void* const* d_in, const int* in_sizes, int n_in,
                              void* d_out, int out_size, void* d_ws,
                              size_t ws_size, hipStream_t stream) {
  (void)in_sizes; (void)n_in; (void)out_size; (void)ws_size;
  const float* query = (const float*)d_in[0];
  const float* refp  = (const float*)d_in[1];
  const float* inpf  = (const float*)d_in[2];
  const float* Woff  = (const float*)d_in[5];
  const float* boff  = (const float*)d_in[6];
  const float* Wattn = (const float*)d_in[7];
  const float* battn = (const float*)d_in[8];
  const float* Wval  = (const float*)d_in[9];
  const float* bval  = (const float*)d_in[10];
  const float* Wout  = (const float*)d_in[11];
  const float* bout  = (const float*)d_in[12];

  // ws: value16 22.3MB | off16 22.3MB | logit16 11.1MB | WT f16 ~0.45MB
  ushort* value16 = (ushort*)d_ws;
  ushort* off16   = value16 + (size_t)MROWS * 256;
  ushort* logit16 = off16 + (size_t)MROWS * 256;
  ushort* WTv     = logit16 + (size_t)MROWS * 128;
  ushort* WTol    = WTv + 65536;   // [384][256]
  ushort* WTu     = WTol + 98304;

  ushort* midb = (ushort*)d_out;   // mid f16 in-place per row (stride 512)

  wt_cvt_all<<<896, 256, 0, stream>>>(Wval, Woff, Wattn, Wout, WTv, WTol, WTu);

  gemm_front<<<680, 512, 0, stream>>>(inpf, WTv, bval, value16, query, WTol,
                                      boff, battn, off16, logit16);

  msda_sample<<<MROWS / 8, 256, 0, stream>>>(off16, logit16, refp, value16,
                                             midb);

  gemm_out<<<MROWS / 128, 512, 0, stream>>>(midb, WTu, bout, (float*)d_out);
}